// Round 6
// baseline (930.253 us; speedup 1.0000x reference)
//
#include <hip/hip_runtime.h>

// Problem constants
#define B_SZ 512
#define T_SZ 512
#define I_SZ 256
#define H_SZ 250

typedef __bf16 bf16x8 __attribute__((ext_vector_type(8)));
typedef __bf16 bf16x4 __attribute__((ext_vector_type(4)));
typedef float  f32x4  __attribute__((ext_vector_type(4)));

__device__ __forceinline__ float fast_tanh(float x) {
    float ax = __builtin_fabsf(x);
    float e  = __expf(-2.0f * ax);          // v_exp_f32 path
    float r  = (1.0f - e) / (1.0f + e);
    return __builtin_copysignf(r, x);
}

// ---------------------------------------------------------------------------
// Kernel 1: xproj[b][t][j] = x[b][t][:] . Wx[j][:] + bh[j]   (written to out)
// M = B*T = 262144 rows, K = 256, N = 250 (padded to 256, 2 N-tiles of 128).
// 128x128 tile per block, 256 threads / 4 waves, bf16 MFMA 16x16x32.
// NEW this round: XCD-aware chunked blockIdx swizzle (T1). Logical tile pairs
// {2k,2k+1} share the same 128 x-rows; chunked remap keeps each pair on one
// XCD so the shared A-panel is an L2 hit on its second read (saves ~130 MB
// of HBM fetch). 4096 % 8 == 0 -> simple form is bijective.
// ---------------------------------------------------------------------------
#define BM 128
#define BN 128
#define BK 32
#define LDT 40   // LDS row stride in bf16 elems (80B, 16B-aligned, conflict-safe)

__global__ __launch_bounds__(256, 2) void xproj_kernel(
    const float* __restrict__ x,    // [M][256]
    const float* __restrict__ Wx,   // [250][256]
    const float* __restrict__ bh,   // [250]
    float* __restrict__ out)        // [M][250]
{
    __shared__ __align__(16) __bf16 As[BM * LDT];
    __shared__ __align__(16) __bf16 Bs[BM * LDT];

    // T1 XCD swizzle: physical block p runs on XCD p%8; logical tile
    // (p%8)*chunk + p/8 gives each XCD a contiguous chunk of tiles.
    const int chunk = gridDim.x >> 3;                          // 512
    const int swz   = (blockIdx.x & 7) * chunk + (blockIdx.x >> 3);
    const int bm = swz >> 1;
    const int bn = swz & 1;
    const int m0 = bm * BM;
    const int n0 = bn * BN;

    const int tid  = threadIdx.x;
    const int lane = tid & 63;
    const int wave = tid >> 6;
    const int wm   = wave >> 1;      // wave row (0/1) -> 64 rows
    const int wn   = wave & 1;       // wave col (0/1) -> 64 cols
    const int l15  = lane & 15;
    const int quad = lane >> 4;

    f32x4 acc[4][4];
#pragma unroll
    for (int i = 0; i < 4; ++i)
#pragma unroll
        for (int j = 0; j < 4; ++j)
            acc[i][j] = (f32x4){0.f, 0.f, 0.f, 0.f};

    for (int kk = 0; kk < I_SZ / BK; ++kk) {
        __syncthreads();   // previous iter's frag reads done
        // stage A (x) and B (Wx) tiles: 128 rows x 32 k, fp32 -> bf16
#pragma unroll
        for (int i = 0; i < 4; ++i) {
            int f   = tid + i * 256;        // float4 index 0..1023
            int row = f >> 3;
            int c4  = f & 7;
            // A
            {
                const float4 v = *(const float4*)&x[(size_t)(m0 + row) * I_SZ + kk * BK + c4 * 4];
                bf16x4 b;
                b[0] = (__bf16)v.x; b[1] = (__bf16)v.y; b[2] = (__bf16)v.z; b[3] = (__bf16)v.w;
                *(bf16x4*)&As[row * LDT + c4 * 4] = b;
            }
            // B (guard rows >= 250)
            {
                int gr = n0 + row;
                bf16x4 b;
                if (gr < H_SZ) {
                    const float4 v = *(const float4*)&Wx[(size_t)gr * I_SZ + kk * BK + c4 * 4];
                    b[0] = (__bf16)v.x; b[1] = (__bf16)v.y; b[2] = (__bf16)v.z; b[3] = (__bf16)v.w;
                } else {
                    b[0] = (__bf16)0.f; b[1] = (__bf16)0.f; b[2] = (__bf16)0.f; b[3] = (__bf16)0.f;
                }
                *(bf16x4*)&Bs[row * LDT + c4 * 4] = b;
            }
        }
        __syncthreads();

        bf16x8 af[4], bfr[4];
#pragma unroll
        for (int tm = 0; tm < 4; ++tm)
            af[tm] = *(const bf16x8*)&As[(wm * 64 + tm * 16 + l15) * LDT + quad * 8];
#pragma unroll
        for (int tn = 0; tn < 4; ++tn)
            bfr[tn] = *(const bf16x8*)&Bs[(wn * 64 + tn * 16 + l15) * LDT + quad * 8];
#pragma unroll
        for (int tm = 0; tm < 4; ++tm)
#pragma unroll
            for (int tn = 0; tn < 4; ++tn)
                acc[tm][tn] = __builtin_amdgcn_mfma_f32_16x16x32_bf16(af[tm], bfr[tn], acc[tm][tn], 0, 0, 0);
    }

    // epilogue: C row = quad*4+reg (m), col = lane&15 (n); add bias
#pragma unroll
    for (int tn = 0; tn < 4; ++tn) {
        int gn = n0 + wn * 64 + tn * 16 + l15;
        if (gn >= H_SZ) continue;
        float bias = bh[gn];
#pragma unroll
        for (int tm = 0; tm < 4; ++tm) {
#pragma unroll
            for (int r = 0; r < 4; ++r) {
                int gm = m0 + wm * 64 + tm * 16 + quad * 4 + r;
                out[(size_t)gm * H_SZ + gn] = acc[tm][tn][r] + bias;
            }
        }
    }
}

// ---------------------------------------------------------------------------
// Kernel 2: recurrence. 256 blocks x 512 threads (8 waves, 2 waves/SIMD).
//  - batches {2b, 2b+1} at A-rows 0 and 4 -> C rows 0,4 -> epilogue on
//    quads 0 AND 1 (r=0), work spread over 32 lanes/wave
//  - j-split 8 ways: each wave owns 32 output cols (2 n-tiles); Wh B-frags
//    held in registers (wf[2][8], 64 VGPRs)
//  - h ping-pong in LDS: 3 rows only (batch0, batch1, zero). A-frag reads:
//    lane l15==0 -> row 0, l15==4 -> row 1, all others broadcast-read the
//    permanently-zero row 2. 12 distinct 16B segments per ds_read_b128,
//    worst-case ~3-way bank aliasing (~1.3x per m136) on 8 reads/step.
//  - xproj prefetched TWO steps ahead (HBM latency ~900cyc > 1 step time)
//  - 4 independent MFMA accumulator chains (2 per n-tile) to break the
//    8-deep dependent-MFMA latency chain
//  - step barrier = s_waitcnt lgkmcnt(0) + raw s_barrier: prefetch loads and
//    output stores stay in flight across the barrier (no vmcnt(0) drain on
//    the 512-step critical path)
// ---------------------------------------------------------------------------
#define HLD 264   // LDS row stride for h (bf16): 528B = +4 banks/row, 16B-mult

__global__ __launch_bounds__(512, 2) void rnn_kernel(
    const float* __restrict__ h0,   // [B][250]
    const float* __restrict__ Wh,   // [250][250]
    float* __restrict__ out)        // [B][T][250], pre-filled with xproj+bias
{
    __shared__ __align__(16) __bf16 hbuf[2][3 * HLD];

    const int b0   = blockIdx.x * 2;
    const int tid  = threadIdx.x;
    const int lane = tid & 63;
    const int wave = tid >> 6;       // 0..7
    const int l15  = lane & 15;
    const int quad = lane >> 4;      // 0..3
    const int j0w  = wave * 32;      // 32 cols per wave

    // zero both buffers: cols >=250 of rows 0/1 and all of row 2 stay 0 forever
    for (int i = tid; i < 2 * 3 * HLD; i += 512)
        ((__bf16*)hbuf)[i] = (__bf16)0.f;
    __syncthreads();

    // init h: batch0 -> row 0, batch1 -> row 1 of buffer 0
    for (int k = tid; k < H_SZ; k += 512) {
        hbuf[0][0 * HLD + k] = (__bf16)h0[(size_t)(b0 + 0) * H_SZ + k];
        hbuf[0][1 * HLD + k] = (__bf16)h0[(size_t)(b0 + 1) * H_SZ + k];
    }

    // Wh fragments in registers: wf[tl][kt], B-frag layout
    // B[k = quad*8 + e][n = lane&15]; n = j0w + tl*16 + l15, k = kt*32 + quad*8 + e
    // B[k][n] = Wh[n][k]  (recurrence needs sum_k h[k] * Wh[j][k])
    bf16x8 wf[2][8];
#pragma unroll
    for (int tl = 0; tl < 2; ++tl) {
        const int j = j0w + tl * 16 + l15;
#pragma unroll
        for (int kt = 0; kt < 8; ++kt) {
            const int kb = kt * 32 + quad * 8;
            bf16x8 v;
#pragma unroll
            for (int e = 0; e < 8; ++e) {
                const int k = kb + e;
                v[e] = (j < H_SZ && k < H_SZ) ? (__bf16)Wh[(size_t)j * H_SZ + k] : (__bf16)0.f;
            }
            wf[tl][kt] = v;
        }
    }
    __syncthreads();

    // per-thread invariants
    // A-frag: lane l15 supplies matrix row m=l15; rows other than 0,4 must be 0.
    // l15==0 -> batch0 (hbuf row 0), l15==4 -> batch1 (hbuf row 1), else zero row 2.
    const int arow = (l15 == 0) ? 0 : ((l15 == 4) ? 1 : 2);
    const int aoff = arow * HLD;
    const int qa   = quad & 1;           // batch select for epilogue quads 0/1
    const int woff = qa * HLD;           // hbuf dest row

    bool   act[2];
    int    jj[2];
    float* xptr[2];
#pragma unroll
    for (int tl = 0; tl < 2; ++tl) {
        jj[tl]  = j0w + tl * 16 + l15;
        act[tl] = (quad < 2) && (jj[tl] < H_SZ);
        const int jc = (jj[tl] < H_SZ) ? jj[tl] : 0;   // keep addr in-range
        xptr[tl] = out + (size_t)(b0 + qa) * T_SZ * H_SZ + jc;
    }

    // xproj shift register: xc = step t, x1 = step t+1 (distance-2 prefetch)
    float xc[2], x1[2];
#pragma unroll
    for (int tl = 0; tl < 2; ++tl) {
        xc[tl] = act[tl] ? xptr[tl][0]    : 0.f;
        x1[tl] = act[tl] ? xptr[tl][H_SZ] : 0.f;
    }

    for (int t = 0; t < T_SZ; ++t) {
        const int cur = t & 1;
        const int nxt = cur ^ 1;

        // prefetch xproj for t+2 (in flight across ~2 full steps)
        float x2[2];
        const bool pf = (t + 2 < T_SZ);
#pragma unroll
        for (int tl = 0; tl < 2; ++tl)
            x2[tl] = (pf && act[tl]) ? xptr[tl][2 * H_SZ] : 0.f;

        // A fragments: A[m = l15][k = kt*32 + quad*8 + e]; zero-row broadcast
        bf16x8 af[8];
#pragma unroll
        for (int kt = 0; kt < 8; ++kt)
            af[kt] = *(const bf16x8*)&hbuf[cur][aoff + kt * 32 + quad * 8];

        // 4 independent accumulator chains (dep distance 4 issue slots)
        f32x4 a0a = (f32x4){0.f, 0.f, 0.f, 0.f};
        f32x4 a0b = (f32x4){0.f, 0.f, 0.f, 0.f};
        f32x4 a1a = (f32x4){0.f, 0.f, 0.f, 0.f};
        f32x4 a1b = (f32x4){0.f, 0.f, 0.f, 0.f};
#pragma unroll
        for (int kt = 0; kt < 4; ++kt) {
            a0a = __builtin_amdgcn_mfma_f32_16x16x32_bf16(af[kt],     wf[0][kt],     a0a, 0, 0, 0);
            a1a = __builtin_amdgcn_mfma_f32_16x16x32_bf16(af[kt],     wf[1][kt],     a1a, 0, 0, 0);
            a0b = __builtin_amdgcn_mfma_f32_16x16x32_bf16(af[kt + 4], wf[0][kt + 4], a0b, 0, 0, 0);
            a1b = __builtin_amdgcn_mfma_f32_16x16x32_bf16(af[kt + 4], wf[1][kt + 4], a1b, 0, 0, 0);
        }

        // epilogue: C row (m) = quad*4 + r, col (n) = lane&15
        // batch0 -> row 0 (quad0,r0), batch1 -> row 4 (quad1,r0)
        const float s[2] = { a0a[0] + a0b[0], a1a[0] + a1b[0] };
#pragma unroll
        for (int tl = 0; tl < 2; ++tl) {
            if (act[tl]) {
                float v = fast_tanh(s[tl] + xc[tl]);
                xptr[tl][0] = v;                              // overwrite xproj with state
                hbuf[nxt][woff + jj[tl]] = (__bf16)v;         // h for next step
            }
            xptr[tl] += H_SZ;
            xc[tl] = x1[tl];
            x1[tl] = x2[tl];
        }

        // end-of-step sync: LDS ops drained, barrier WITHOUT vmcnt drain
        // (prefetch loads + global stores stay in flight)
        asm volatile("s_waitcnt lgkmcnt(0)" ::: "memory");
        __builtin_amdgcn_s_barrier();
        asm volatile("" ::: "memory");
    }
}

extern "C" void kernel_launch(void* const* d_in, const int* in_sizes, int n_in,
                              void* d_out, int out_size, void* d_ws, size_t ws_size,
                              hipStream_t stream) {
    const float* x  = (const float*)d_in[0];
    const float* h  = (const float*)d_in[1];
    const float* Wx = (const float*)d_in[2];
    const float* Wh = (const float*)d_in[3];
    const float* bh = (const float*)d_in[4];
    float* out = (float*)d_out;

    const int M = B_SZ * T_SZ;                 // 262144
    xproj_kernel<<<dim3((M / BM) * 2), dim3(256), 0, stream>>>(x, Wx, bh, out);
    rnn_kernel<<<dim3(B_SZ / 2), dim3(512), 0, stream>>>(h, Wh, out);
}